// Round 6
// baseline (220.896 us; speedup 1.0000x reference)
//
#include <hip/hip_runtime.h>

typedef short short8 __attribute__((ext_vector_type(8)));
typedef float floatx4 __attribute__((ext_vector_type(4)));
typedef unsigned short ushort_t;

#define EMBED 1024
#define HEADS 16
#define HD 64
#define SEQ 2048
#define BATCH 2

__device__ inline ushort_t f2bf(float f) {
    unsigned int u = __float_as_uint(f);
    u += 0x7fff + ((u >> 16) & 1);   // round-to-nearest-even
    return (ushort_t)(u >> 16);
}

// async global->LDS, 16B per lane. LDS dest = wave-uniform base + lane*16.
typedef const __attribute__((address_space(1))) unsigned int* gas_t;
typedef __attribute__((address_space(3))) unsigned int* las_t;
__device__ inline void async_copy16(const ushort_t* g, ushort_t* l) {
    __builtin_amdgcn_global_load_lds((gas_t)g, (las_t)l, 16, 0, 0);
}

// ---------------- fused cast fp32 -> bf16 (3 tensors, 1 launch) -----------
__global__ void cast3_kernel(const float* __restrict__ a, ushort_t* __restrict__ oa, int na,
                             const float* __restrict__ b, ushort_t* __restrict__ ob, int nb,
                             const float* __restrict__ c, ushort_t* __restrict__ oc, int nc) {
    int idx = (blockIdx.x * blockDim.x + threadIdx.x) * 4;
    const float* in; ushort_t* out;
    if (idx < na)            { in = a;  out = oa; }
    else if (idx < na + nb)  { in = b;  out = ob; idx -= na; }
    else if (idx < na + nb + nc) { in = c; out = oc; idx -= na + nb; }
    else return;
    float4 f = *(const float4*)(in + idx);
    ushort4 o;
    o.x = f2bf(f.x); o.y = f2bf(f.y); o.z = f2bf(f.z); o.w = f2bf(f.w);
    *(ushort4*)(out + idx) = o;
}

// ---------------- GEMM (m97 structure + XCD swizzle): Y = A * B^T ---------
// 1D grid; xcd = id%8 owns a contiguous 4-block m-strip (A strip 1MB hot in
// its private L2); within XCD, bn-major order keeps the current B tile hot.
#define BM 128
#define BN 128
#define BK 32

template<int MODE>
__launch_bounds__(256, 3)
__global__ void gemm_bt(const ushort_t* __restrict__ A, const ushort_t* __restrict__ B,
                        float* __restrict__ outF,
                        ushort_t* __restrict__ qb, ushort_t* __restrict__ kb,
                        ushort_t* __restrict__ vtb,
                        int M, int N, int K) {
    __shared__ ushort_t As[BM * BK];   // 8KB, unpadded (DMA dest), swizzled granules
    __shared__ ushort_t Bs[BN * BK];
    const int id   = blockIdx.x;
    const int jj   = id >> 3;
    const int bm   = (id & 7) * 4 + (jj & 3);   // M=4096 -> 32 m-blocks, 4 per XCD
    const int bn   = jj >> 2;
    const int t    = threadIdx.x;
    const int lane = t & 63;
    const int wave = t >> 6;
    const int wm   = (wave >> 1) * 64;
    const int wn   = (wave & 1) * 64;
    const int m0   = bm * BM;
    const int n0   = bn * BN;
    const int col  = lane & 15;
    const int quad = lane >> 4;

    const int srow = lane >> 2;
    const int sgr  = (lane & 3) ^ (srow & 3);
    const int rslot = quad ^ (col & 3);

    floatx4 acc[4][4] = {};

    for (int k0 = 0; k0 < K; k0 += BK) {
        for (int half = 0; half < 2; ++half) {
            int row0 = wave * 32 + half * 16;
            int r = row0 + srow;
            async_copy16(A + (size_t)(m0 + r) * K + k0 + sgr * 8, &As[row0 * BK]);
            async_copy16(B + (size_t)(n0 + r) * K + k0 + sgr * 8, &Bs[row0 * BK]);
        }
        __syncthreads();
        short8 a[4], b[4];
        for (int i = 0; i < 4; ++i)
            a[i] = *(const short8*)(&As[(wm + i * 16 + col) * BK + rslot * 8]);
        for (int j = 0; j < 4; ++j)
            b[j] = *(const short8*)(&Bs[(wn + j * 16 + col) * BK + rslot * 8]);
        for (int i = 0; i < 4; ++i)
            for (int j = 0; j < 4; ++j)
                acc[i][j] = __builtin_amdgcn_mfma_f32_16x16x32_bf16(a[i], b[j], acc[i][j], 0, 0, 0);
        __syncthreads();
    }

    for (int i = 0; i < 4; ++i)
        for (int j = 0; j < 4; ++j)
            for (int r = 0; r < 4; ++r) {
                int m = m0 + wm + i * 16 + quad * 4 + r;
                int n = n0 + wn + j * 16 + col;
                float c = acc[i][j][r];
                if (MODE == 1) {
                    outF[(size_t)m * N + n] = c;
                } else {
                    int part = n >> 10;          // 0=q 1=k 2=v
                    int within = n & 1023;
                    int h = within >> 6, d = within & 63;
                    int bb = m >> 11, s = m & 2047;
                    ushort_t v = f2bf(c);
                    if (part == 0)      qb [(((size_t)bb * HEADS + h) * SEQ + s) * HD + d] = v;
                    else if (part == 1) kb [(((size_t)bb * HEADS + h) * SEQ + s) * HD + d] = v;
                    else                vtb[(((size_t)bb * HEADS + h) * HD + d) * SEQ + s] = v;
                }
            }
}

// ---------------- flash-style attention v5 ----------------
// 64 q/block (16/wave), 1024 blocks (4 bh per XCD -> KV 2MB/XCD hot in L2),
// LDS 42KB -> 3 blocks/CU resident: cross-block overlap covers DMA drains.
#define LDP 72

__launch_bounds__(256, 3)
__global__ void attn_kernel(const ushort_t* __restrict__ qb_, const ushort_t* __restrict__ kb,
                            const ushort_t* __restrict__ vtb, ushort_t* __restrict__ attn) {
    __shared__ ushort_t Klds[2][64 * 64];
    __shared__ ushort_t Vlds[2][64 * 64];
    __shared__ ushort_t Plds[4][16 * LDP];
    const int id   = blockIdx.x;           // 1024 blocks
    const int jj   = id >> 3;              // 0..127
    const int bh   = (id & 7) * 4 + (jj >> 5);
    const int qblk = jj & 31;
    const int t    = threadIdx.x;
    const int lane = t & 63;
    const int wave = t >> 6;
    const int col  = lane & 15;
    const int quad = lane >> 4;
    const int q0   = qblk * 64 + wave * 16;

    const ushort_t* Q  = qb_ + (size_t)bh * SEQ * HD;
    const ushort_t* Kp = kb  + (size_t)bh * SEQ * HD;
    const ushort_t* Vt = vtb + (size_t)bh * HD * SEQ;

    const int srow = lane >> 3;       // 0..7 within instr (128B rows)
    const int sgr  = lane & 7;        // granule slot 0..7

    short8 qf0 = *(const short8*)(Q + (size_t)(q0 + col) * HD + quad * 8);
    short8 qf1 = *(const short8*)(Q + (size_t)(q0 + col) * HD + 32 + quad * 8);

    floatx4 acc[4] = {};
    float lsum = 0.f;
    const float SC = 0.125f * 1.44269504f;  // log2(e)/sqrt(hd)
    const int sw = col & 7;                  // read-side swizzle

    auto stage = [&](int kt, int buf) {
        for (int inst = 0; inst < 2; ++inst) {
            int row0 = wave * 16 + inst * 8;
            int r = row0 + srow;
            const ushort_t* gk = Kp + (size_t)(kt + r) * HD + ((sgr ^ (r & 7)) * 8);
            async_copy16(gk, &Klds[buf][row0 * 64]);
            const ushort_t* gv = Vt + (size_t)r * SEQ + kt + ((sgr ^ (r & 7)) * 8);
            async_copy16(gv, &Vlds[buf][row0 * 64]);
        }
    };

    stage(0, 0);
    __syncthreads();

    for (int kt = 0; kt < SEQ; kt += 64) {
        const int cur = (kt >> 6) & 1;
        stage((kt + 64) & (SEQ - 1), cur ^ 1);   // async prefetch next chunk

        const ushort_t* Kc = Klds[cur];
        const ushort_t* Vc = Vlds[cur];

        short8 kf[4][2];
        for (int n = 0; n < 4; ++n) {
            int row = n * 16 + col;
            kf[n][0] = *(const short8*)(Kc + row * 64 + ((quad ^ sw) * 8));
            kf[n][1] = *(const short8*)(Kc + row * 64 + (((4 + quad) ^ sw) * 8));
        }
        for (int n = 0; n < 4; ++n) {
            floatx4 z = {};
            z = __builtin_amdgcn_mfma_f32_16x16x32_bf16(kf[n][0], qf0, z, 0, 0, 0);
            z = __builtin_amdgcn_mfma_f32_16x16x32_bf16(kf[n][1], qf1, z, 0, 0, 0);
            // exp2 then truncate to bf16; lsum from the SAME truncated values
            unsigned int u0 = __float_as_uint(__builtin_amdgcn_exp2f(z[0] * SC));
            unsigned int u1 = __float_as_uint(__builtin_amdgcn_exp2f(z[1] * SC));
            unsigned int u2 = __float_as_uint(__builtin_amdgcn_exp2f(z[2] * SC));
            unsigned int u3 = __float_as_uint(__builtin_amdgcn_exp2f(z[3] * SC));
            lsum += (__uint_as_float(u0 & 0xffff0000u) + __uint_as_float(u1 & 0xffff0000u))
                  + (__uint_as_float(u2 & 0xffff0000u) + __uint_as_float(u3 & 0xffff0000u));
            uint2 pk;
            pk.x = __builtin_amdgcn_perm(u1, u0, 0x07060302u);  // lo16=u0>>16, hi16=u1>>16
            pk.y = __builtin_amdgcn_perm(u3, u2, 0x07060302u);
            *(uint2*)(&Plds[wave][col * LDP + n * 16 + quad * 4]) = pk;
        }
        short8 vf[4][2];
        for (int d = 0; d < 4; ++d) {
            int row = d * 16 + col;
            vf[d][0] = *(const short8*)(Vc + row * 64 + ((quad ^ sw) * 8));
            vf[d][1] = *(const short8*)(Vc + row * 64 + (((4 + quad) ^ sw) * 8));
        }
        short8 pf0 = *(const short8*)(&Plds[wave][col * LDP + quad * 8]);
        short8 pf1 = *(const short8*)(&Plds[wave][col * LDP + 32 + quad * 8]);
        for (int d = 0; d < 4; ++d) {
            acc[d] = __builtin_amdgcn_mfma_f32_16x16x32_bf16(pf0, vf[d][0], acc[d], 0, 0, 0);
            acc[d] = __builtin_amdgcn_mfma_f32_16x16x32_bf16(pf1, vf[d][1], acc[d], 0, 0, 0);
        }
        __syncthreads();   // drains prefetch DMA + all waves' reads of cur buffer
    }

    float s = lsum;
    s += __shfl_xor(s, 16);
    s += __shfl_xor(s, 32);      // lane holds full sum for q = q0+col
    float inv[4];
    for (int r = 0; r < 4; ++r)
        inv[r] = 1.0f / __shfl(s, quad * 4 + r);

    int b = bh >> 4, h = bh & 15;
    for (int d = 0; d < 4; ++d)
        for (int r = 0; r < 4; ++r) {
            int row = q0 + quad * 4 + r;
            int cc  = h * HD + d * 16 + col;
            attn[((size_t)b * SEQ + row) * EMBED + cc] = f2bf(acc[d][r] * inv[r]);
        }
}

// ---------------- launch ----------------
extern "C" void kernel_launch(void* const* d_in, const int* in_sizes, int n_in,
                              void* d_out, int out_size, void* d_ws, size_t ws_size,
                              hipStream_t stream) {
    const float* x     = (const float*)d_in[0];   // [2,2048,1024]
    const float* w_qkv = (const float*)d_in[1];   // [3072,1024]
    const float* w_out = (const float*)d_in[2];   // [1024,1024]
    float* out = (float*)d_out;                   // [2,2048,1024] fp32

    char* ws = (char*)d_ws;
    size_t off = 0;
    ushort_t* x_bf    = (ushort_t*)(ws + off); off += (size_t)BATCH * SEQ * EMBED * 2;
    ushort_t* wqkv_bf = (ushort_t*)(ws + off); off += (size_t)3 * EMBED * EMBED * 2;
    ushort_t* wout_bf = (ushort_t*)(ws + off); off += (size_t)EMBED * EMBED * 2;
    ushort_t* q_buf   = (ushort_t*)(ws + off); off += (size_t)BATCH * HEADS * SEQ * HD * 2;
    ushort_t* k_buf   = (ushort_t*)(ws + off); off += (size_t)BATCH * HEADS * SEQ * HD * 2;
    ushort_t* vt_buf  = (ushort_t*)(ws + off); off += (size_t)BATCH * HEADS * SEQ * HD * 2;
    ushort_t* attn_bf = (ushort_t*)(ws + off); off += (size_t)BATCH * SEQ * EMBED * 2;

    int n_x = BATCH * SEQ * EMBED, n_wq = 3 * EMBED * EMBED, n_wo = EMBED * EMBED;
    int n_all = n_x + n_wq + n_wo;
    cast3_kernel<<<n_all / 1024, 256, 0, stream>>>(x, x_bf, n_x, w_qkv, wqkv_bf, n_wq,
                                                   w_out, wout_bf, n_wo);

    // qkv = x @ w_qkv^T : M=4096, N=3072, K=1024 -> 32x24 = 768 blocks
    gemm_bt<0><<<768, 256, 0, stream>>>(
        x_bf, wqkv_bf, nullptr, q_buf, k_buf, vt_buf, BATCH * SEQ, 3 * EMBED, EMBED);

    attn_kernel<<<1024, 256, 0, stream>>>(q_buf, k_buf, vt_buf, attn_bf);

    // out = attn @ w_out^T : M=4096, N=1024, K=1024 -> 32x8 = 256 blocks
    gemm_bt<1><<<256, 256, 0, stream>>>(
        attn_bf, wout_bf, out, nullptr, nullptr, nullptr, BATCH * SEQ, EMBED, EMBED);
}

// Round 7
// 177.822 us; speedup vs baseline: 1.2422x; 1.2422x over previous
//
#include <hip/hip_runtime.h>

typedef short short8 __attribute__((ext_vector_type(8)));
typedef short short4v __attribute__((ext_vector_type(4)));
typedef float floatx4 __attribute__((ext_vector_type(4)));
typedef unsigned short ushort_t;

#define EMBED 1024
#define HEADS 16
#define HD 64
#define SEQ 2048
#define BATCH 2

__device__ inline ushort_t f2bf(float f) {
    unsigned int u = __float_as_uint(f);
    u += 0x7fff + ((u >> 16) & 1);   // round-to-nearest-even
    return (ushort_t)(u >> 16);
}

// async global->LDS, 16B per lane. LDS dest = wave-uniform base + lane*16.
typedef const __attribute__((address_space(1))) unsigned int* gas_t;
typedef __attribute__((address_space(3))) unsigned int* las_t;
__device__ inline void async_copy16(const ushort_t* g, ushort_t* l) {
    __builtin_amdgcn_global_load_lds((gas_t)g, (las_t)l, 16, 0, 0);
}

// ---------------- fused cast fp32 -> bf16 (3 tensors, 1 launch) -----------
__global__ void cast3_kernel(const float* __restrict__ a, ushort_t* __restrict__ oa, int na,
                             const float* __restrict__ b, ushort_t* __restrict__ ob, int nb,
                             const float* __restrict__ c, ushort_t* __restrict__ oc, int nc) {
    int idx = (blockIdx.x * blockDim.x + threadIdx.x) * 4;
    const float* in; ushort_t* out;
    if (idx < na)            { in = a;  out = oa; }
    else if (idx < na + nb)  { in = b;  out = ob; idx -= na; }
    else if (idx < na + nb + nc) { in = c; out = oc; idx -= na + nb; }
    else return;
    float4 f = *(const float4*)(in + idx);
    ushort4 o;
    o.x = f2bf(f.x); o.y = f2bf(f.y); o.z = f2bf(f.z); o.w = f2bf(f.w);
    *(ushort4*)(out + idx) = o;
}

// ---------------- GEMM (BK=64, XCD swizzle): Y = A * B^T ------------------
// 16 K-iterations (vs 32): half the barrier drains, 32 MFMAs/wave-iter.
#define BM 128
#define BN 128
#define BK 64

template<int MODE>
__launch_bounds__(256, 3)
__global__ void gemm_bt(const ushort_t* __restrict__ A, const ushort_t* __restrict__ B,
                        float* __restrict__ outF,
                        ushort_t* __restrict__ qb, ushort_t* __restrict__ kb,
                        ushort_t* __restrict__ vtb,
                        int M, int N, int K) {
    __shared__ ushort_t As[BM * BK];   // 16KB, unpadded (DMA dest), XOR-swizzled granules
    __shared__ ushort_t Bs[BN * BK];   // 16KB
    const int id   = blockIdx.x;
    const int jj   = id >> 3;
    const int bm   = (id & 7) * 4 + (jj & 3);   // 4 m-blocks per XCD
    const int bn   = jj >> 2;
    const int t    = threadIdx.x;
    const int lane = t & 63;
    const int wave = t >> 6;
    const int wm   = (wave >> 1) * 64;
    const int wn   = (wave & 1) * 64;
    const int m0   = bm * BM;
    const int n0   = bn * BN;
    const int col  = lane & 15;
    const int quad = lane >> 4;

    // staging: one DMA instr = 64 lanes x 16B = 8 rows x 128B.
    // lane i -> row i>>3, LDS slot i&7; global granule = slot ^ (row&7).
    const int srow = lane >> 3;
    const int sgr  = (lane & 7) ^ (srow & 7);
    // fragment read: global granule g of row r lives in LDS slot g ^ (r&7);
    // r&7 == col&7 (bases are multiples of 16).
    const int slot0 = quad ^ (col & 7);          // granules 0..3  (k 0..31)

    floatx4 acc[4][4] = {};

    for (int k0 = 0; k0 < K; k0 += BK) {
        for (int half = 0; half < 4; ++half) {
            int row0 = wave * 32 + half * 8;
            int r = row0 + srow;
            async_copy16(A + (size_t)(m0 + r) * K + k0 + sgr * 8, &As[row0 * BK]);
            async_copy16(B + (size_t)(n0 + r) * K + k0 + sgr * 8, &Bs[row0 * BK]);
        }
        __syncthreads();
        short8 a[2][4], b[2][4];
        for (int i = 0; i < 4; ++i) {
            int base = (wm + i * 16 + col) * BK;
            a[0][i] = *(const short8*)(&As[base + slot0 * 8]);
            a[1][i] = *(const short8*)(&As[base + (slot0 ^ 4) * 8]);
        }
        for (int j = 0; j < 4; ++j) {
            int base = (wn + j * 16 + col) * BK;
            b[0][j] = *(const short8*)(&Bs[base + slot0 * 8]);
            b[1][j] = *(const short8*)(&Bs[base + (slot0 ^ 4) * 8]);
        }
        for (int kk = 0; kk < 2; ++kk)
            for (int i = 0; i < 4; ++i)
                for (int j = 0; j < 4; ++j)
                    acc[i][j] = __builtin_amdgcn_mfma_f32_16x16x32_bf16(a[kk][i], b[kk][j], acc[i][j], 0, 0, 0);
        __syncthreads();
    }

    for (int i = 0; i < 4; ++i)
        for (int j = 0; j < 4; ++j) {
            int n = n0 + wn + j * 16 + col;
            int mb = m0 + wm + i * 16 + quad * 4;   // 4 consecutive m
            if (MODE == 1) {
                for (int r = 0; r < 4; ++r)
                    outF[(size_t)(mb + r) * N + n] = acc[i][j][r];
            } else {
                int part = n >> 10;          // 0=q 1=k 2=v
                int within = n & 1023;
                int h = within >> 6, d = within & 63;
                int bb = mb >> 11, s = mb & 2047;
                if (part == 2) {
                    // vT[(bb,h,d), s]: consecutive r = consecutive s -> short4
                    short4v pv;
                    pv.x = (short)f2bf(acc[i][j][0]); pv.y = (short)f2bf(acc[i][j][1]);
                    pv.z = (short)f2bf(acc[i][j][2]); pv.w = (short)f2bf(acc[i][j][3]);
                    *(short4v*)(vtb + (((size_t)bb * HEADS + h) * HD + d) * SEQ + s) = pv;
                } else {
                    ushort_t* dst = (part == 0) ? qb : kb;
                    for (int r = 0; r < 4; ++r)
                        dst[(((size_t)bb * HEADS + h) * SEQ + s + r) * HD + d] = f2bf(acc[i][j][r]);
                }
            }
        }
}

// ---------------- flash-style attention v6 (v4 geometry + XCD swizzle) ----
// 128 q/block (32/wave, qt=2), 512 blocks, 4 bh per XCD (KV 2MB/XCD in L2).
#define LDP 72

__launch_bounds__(256, 3)
__global__ void attn_kernel(const ushort_t* __restrict__ qb_, const ushort_t* __restrict__ kb,
                            const ushort_t* __restrict__ vtb, ushort_t* __restrict__ attn) {
    __shared__ ushort_t Klds[2][64 * 64];
    __shared__ ushort_t Vlds[2][64 * 64];
    __shared__ ushort_t Plds[4][2][16 * LDP];
    const int id   = blockIdx.x;             // 512 blocks
    const int jj   = id >> 3;                // 0..63
    const int bh   = (id & 7) * 4 + (jj >> 4);
    const int qblk = jj & 15;
    const int t    = threadIdx.x;
    const int lane = t & 63;
    const int wave = t >> 6;
    const int col  = lane & 15;
    const int quad = lane >> 4;
    const int q0   = qblk * 128 + wave * 32;

    const ushort_t* Q  = qb_ + (size_t)bh * SEQ * HD;
    const ushort_t* Kp = kb  + (size_t)bh * SEQ * HD;
    const ushort_t* Vt = vtb + (size_t)bh * HD * SEQ;

    const int srow = lane >> 3;       // 0..7 within instr (128B rows)
    const int sgr  = lane & 7;        // granule slot 0..7

    short8 qf[2][2];
    for (int qt = 0; qt < 2; ++qt) {
        qf[qt][0] = *(const short8*)(Q + (size_t)(q0 + qt * 16 + col) * HD + quad * 8);
        qf[qt][1] = *(const short8*)(Q + (size_t)(q0 + qt * 16 + col) * HD + 32 + quad * 8);
    }

    floatx4 acc[2][4] = {};
    float lsum[2] = {0.f, 0.f};
    const float SC = 0.125f * 1.44269504f;  // log2(e)/sqrt(hd)
    const int sw = col & 7;                  // read-side swizzle

    auto stage = [&](int kt, int buf) {
        for (int inst = 0; inst < 2; ++inst) {
            int row0 = wave * 16 + inst * 8;
            int r = row0 + srow;
            const ushort_t* gk = Kp + (size_t)(kt + r) * HD + ((sgr ^ (r & 7)) * 8);
            async_copy16(gk, &Klds[buf][row0 * 64]);
            const ushort_t* gv = Vt + (size_t)r * SEQ + kt + ((sgr ^ (r & 7)) * 8);
            async_copy16(gv, &Vlds[buf][row0 * 64]);
        }
    };

    stage(0, 0);
    __syncthreads();

    for (int kt = 0; kt < SEQ; kt += 64) {
        const int cur = (kt >> 6) & 1;
        stage((kt + 64) & (SEQ - 1), cur ^ 1);   // async prefetch next chunk

        const ushort_t* Kc = Klds[cur];
        const ushort_t* Vc = Vlds[cur];

        short8 kf[4][2];
        for (int n = 0; n < 4; ++n) {
            int row = n * 16 + col;
            kf[n][0] = *(const short8*)(Kc + row * 64 + ((quad ^ sw) * 8));
            kf[n][1] = *(const short8*)(Kc + row * 64 + (((4 + quad) ^ sw) * 8));
        }
        for (int qt = 0; qt < 2; ++qt)
            for (int n = 0; n < 4; ++n) {
                floatx4 z = {};
                z = __builtin_amdgcn_mfma_f32_16x16x32_bf16(kf[n][0], qf[qt][0], z, 0, 0, 0);
                z = __builtin_amdgcn_mfma_f32_16x16x32_bf16(kf[n][1], qf[qt][1], z, 0, 0, 0);
                // exp2 then truncate to bf16; lsum from the SAME truncated values
                unsigned int u0 = __float_as_uint(__builtin_amdgcn_exp2f(z[0] * SC));
                unsigned int u1 = __float_as_uint(__builtin_amdgcn_exp2f(z[1] * SC));
                unsigned int u2 = __float_as_uint(__builtin_amdgcn_exp2f(z[2] * SC));
                unsigned int u3 = __float_as_uint(__builtin_amdgcn_exp2f(z[3] * SC));
                lsum[qt] += (__uint_as_float(u0 & 0xffff0000u) + __uint_as_float(u1 & 0xffff0000u))
                          + (__uint_as_float(u2 & 0xffff0000u) + __uint_as_float(u3 & 0xffff0000u));
                uint2 pk;
                pk.x = __builtin_amdgcn_perm(u1, u0, 0x07060302u);  // lo16=u0>>16, hi16=u1>>16
                pk.y = __builtin_amdgcn_perm(u3, u2, 0x07060302u);
                *(uint2*)(&Plds[wave][qt][col * LDP + n * 16 + quad * 4]) = pk;
            }
        short8 vf[4][2];
        for (int d = 0; d < 4; ++d) {
            int row = d * 16 + col;
            vf[d][0] = *(const short8*)(Vc + row * 64 + ((quad ^ sw) * 8));
            vf[d][1] = *(const short8*)(Vc + row * 64 + (((4 + quad) ^ sw) * 8));
        }
        for (int qt = 0; qt < 2; ++qt) {
            short8 pf0 = *(const short8*)(&Plds[wave][qt][col * LDP + quad * 8]);
            short8 pf1 = *(const short8*)(&Plds[wave][qt][col * LDP + 32 + quad * 8]);
            for (int d = 0; d < 4; ++d) {
                acc[qt][d] = __builtin_amdgcn_mfma_f32_16x16x32_bf16(pf0, vf[d][0], acc[qt][d], 0, 0, 0);
                acc[qt][d] = __builtin_amdgcn_mfma_f32_16x16x32_bf16(pf1, vf[d][1], acc[qt][d], 0, 0, 0);
            }
        }
        __syncthreads();   // drains prefetch DMA + all waves' reads of cur buffer
    }

    int b = bh >> 4, h = bh & 15;
    for (int qt = 0; qt < 2; ++qt) {
        float s = lsum[qt];
        s += __shfl_xor(s, 16);
        s += __shfl_xor(s, 32);
        float inv[4];
        for (int r = 0; r < 4; ++r)
            inv[r] = 1.0f / __shfl(s, quad * 4 + r);
        for (int d = 0; d < 4; ++d)
            for (int r = 0; r < 4; ++r) {
                int row = q0 + qt * 16 + quad * 4 + r;
                int cc  = h * HD + d * 16 + col;
                attn[((size_t)b * SEQ + row) * EMBED + cc] = f2bf(acc[qt][d][r] * inv[r]);
            }
    }
}

// ---------------- launch ----------------
extern "C" void kernel_launch(void* const* d_in, const int* in_sizes, int n_in,
                              void* d_out, int out_size, void* d_ws, size_t ws_size,
                              hipStream_t stream) {
    const float* x     = (const float*)d_in[0];   // [2,2048,1024]
    const float* w_qkv = (const float*)d_in[1];   // [3072,1024]
    const float* w_out = (const float*)d_in[2];   // [1024,1024]
    float* out = (float*)d_out;                   // [2,2048,1024] fp32

    char* ws = (char*)d_ws;
    size_t off = 0;
    ushort_t* x_bf    = (ushort_t*)(ws + off); off += (size_t)BATCH * SEQ * EMBED * 2;
    ushort_t* wqkv_bf = (ushort_t*)(ws + off); off += (size_t)3 * EMBED * EMBED * 2;
    ushort_t* wout_bf = (ushort_t*)(ws + off); off += (size_t)EMBED * EMBED * 2;
    ushort_t* q_buf   = (ushort_t*)(ws + off); off += (size_t)BATCH * HEADS * SEQ * HD * 2;
    ushort_t* k_buf   = (ushort_t*)(ws + off); off += (size_t)BATCH * HEADS * SEQ * HD * 2;
    ushort_t* vt_buf  = (ushort_t*)(ws + off); off += (size_t)BATCH * HEADS * SEQ * HD * 2;
    ushort_t* attn_bf = (ushort_t*)(ws + off); off += (size_t)BATCH * SEQ * EMBED * 2;

    int n_x = BATCH * SEQ * EMBED, n_wq = 3 * EMBED * EMBED, n_wo = EMBED * EMBED;
    int n_all = n_x + n_wq + n_wo;
    cast3_kernel<<<n_all / 1024, 256, 0, stream>>>(x, x_bf, n_x, w_qkv, wqkv_bf, n_wq,
                                                   w_out, wout_bf, n_wo);

    // qkv = x @ w_qkv^T : M=4096, N=3072, K=1024 -> 32x24 = 768 blocks
    gemm_bt<0><<<768, 256, 0, stream>>>(
        x_bf, wqkv_bf, nullptr, q_buf, k_buf, vt_buf, BATCH * SEQ, 3 * EMBED, EMBED);

    attn_kernel<<<512, 256, 0, stream>>>(q_buf, k_buf, vt_buf, attn_bf);

    // out = attn @ w_out^T : M=4096, N=1024, K=1024 -> 32x8 = 256 blocks
    gemm_bt<1><<<256, 256, 0, stream>>>(
        attn_bf, wout_bf, out, nullptr, nullptr, nullptr, BATCH * SEQ, EMBED, EMBED);
}